// Round 12
// baseline (288.240 us; speedup 1.0000x reference)
//
#include <hip/hip_runtime.h>

typedef __bf16 bf16_t;
typedef bf16_t bf16x8 __attribute__((ext_vector_type(8)));
typedef bf16_t bf16x4 __attribute__((ext_vector_type(4)));
typedef float f32x4 __attribute__((ext_vector_type(4)));
typedef float f32x16 __attribute__((ext_vector_type(16)));

#define MFMA16(a, b, c) __builtin_amdgcn_mfma_f32_16x16x32_bf16(a, b, c, 0, 0, 0)
#define MFMA32(a, b, c) __builtin_amdgcn_mfma_f32_32x32x16_bf16(a, b, c, 0, 0, 0)

#define GLOAD16(gsrc, ldst)                                            \
  __builtin_amdgcn_global_load_lds(                                    \
      (const __attribute__((address_space(1))) void*)(gsrc),           \
      (__attribute__((address_space(3))) void*)(ldst), 16, 0, 0)

constexpr int B_ = 2, S_ = 2048, H_ = 2048, NH = 32, NKV = 8, HD = 64;
constexpr int NQKV = NH * HD + 2 * NKV * HD;   // 3072
constexpr int M_ROWS = B_ * S_;                // 4096
constexpr float QSCALE = 0.125f * 1.4426950408889634f;  // score-scale * log2(e) folded into q

// ---------------- f32 -> bf16 convert (8 elems/thread) ----------------
__global__ __launch_bounds__(256) void cvt_kernel(const float* __restrict__ in,
                                                  bf16_t* __restrict__ out, int n8) {
  int i = blockIdx.x * 256 + threadIdx.x;
  if (i >= n8) return;
  const float4* p = (const float4*)(in + (size_t)i * 8);
  float4 a = p[0], b = p[1];
  bf16x8 o;
  o[0] = (bf16_t)a.x; o[1] = (bf16_t)a.y; o[2] = (bf16_t)a.z; o[3] = (bf16_t)a.w;
  o[4] = (bf16_t)b.x; o[5] = (bf16_t)b.y; o[6] = (bf16_t)b.z; o[7] = (bf16_t)b.w;
  *(bf16x8*)(out + (size_t)i * 8) = o;
}

// Wq (524288x8) + Wk (131072x8) + Wv (131072x8) -> contiguous wqkv
__global__ __launch_bounds__(256) void cvt3_kernel(const float* __restrict__ s0,
                                                   const float* __restrict__ s1,
                                                   const float* __restrict__ s2,
                                                   bf16_t* __restrict__ out) {
  int i = blockIdx.x * 256 + threadIdx.x;
  const float* src;
  long off;
  if (i < 524288) { src = s0; off = i; }
  else if (i < 655360) { src = s1; off = i - 524288; }
  else { src = s2; off = i - 655360; }
  const float4* p = (const float4*)(src + off * 8);
  float4 a = p[0], b = p[1];
  bf16x8 o;
  o[0] = (bf16_t)a.x; o[1] = (bf16_t)a.y; o[2] = (bf16_t)a.z; o[3] = (bf16_t)a.w;
  o[4] = (bf16_t)b.x; o[5] = (bf16_t)b.y; o[6] = (bf16_t)b.z; o[7] = (bf16_t)b.w;
  *(bf16x8*)(out + (size_t)i * 8) = o;
}

// ---------------- GEMM: C(MxN) = A(MxK) * B(NxK)^T, bf16 in, f32 acc ----------------
// 128x128 tile, BK=32, 4 waves (2x2). global_load_lds(16B) staging, double-buffered,
// source-pre-swizzled LDS for conflict-free ds_read_b128. (round-3 proven form)
template <bool OUT_BF16>
__global__ __launch_bounds__(256) void gemm_bt(const bf16_t* __restrict__ A,
                                               const bf16_t* __restrict__ Bm,
                                               float* __restrict__ Cf,
                                               bf16_t* __restrict__ Cb,
                                               int M, int N, int K) {
  __shared__ __align__(16) bf16_t As[2][128 * 32];
  __shared__ __align__(16) bf16_t Bs[2][128 * 32];
  const int t = threadIdx.x;
  const int lane = t & 63, w = t >> 6;
  const int l15 = lane & 15, l4 = lane >> 4;
  const int wm = w >> 1, wn = w & 1;
  const long Ar0 = (long)blockIdx.y * 128;
  const long Br0 = (long)blockIdx.x * 128;
  const int nt = K >> 5;

  const int scol = ((lane & 3) ^ ((lane >> 3) & 3)) * 8;
  const int srow = lane >> 2;
  auto stage = [&](int kt, int buf) {
#pragma unroll
    for (int c = 0; c < 2; ++c) {
      const int i = w * 2 + c;
      const bf16_t* gA = A + (Ar0 + i * 16 + srow) * (long)K + kt * 32 + scol;
      const bf16_t* gB = Bm + (Br0 + i * 16 + srow) * (long)K + kt * 32 + scol;
      GLOAD16(gA, &As[buf][i * 512]);
      GLOAD16(gB, &Bs[buf][i * 512]);
    }
  };

  f32x4 acc[4][4] = {};
  stage(0, 0);
  __syncthreads();
  int cur = 0;
  const int rsw = l4 ^ ((l15 >> 1) & 3);
  for (int kt = 0; kt < nt; ++kt) {
    if (kt + 1 < nt) stage(kt + 1, cur ^ 1);
    bf16x8 af[4], bfr[4];
#pragma unroll
    for (int mf = 0; mf < 4; ++mf)
      af[mf] = *(const bf16x8*)&As[cur][(wm * 64 + mf * 16 + l15) * 32 + rsw * 8];
#pragma unroll
    for (int nf = 0; nf < 4; ++nf)
      bfr[nf] = *(const bf16x8*)&Bs[cur][(wn * 64 + nf * 16 + l15) * 32 + rsw * 8];
#pragma unroll
    for (int mf = 0; mf < 4; ++mf)
#pragma unroll
      for (int nf = 0; nf < 4; ++nf)
        acc[mf][nf] = MFMA16(af[mf], bfr[nf], acc[mf][nf]);
    __syncthreads();
    cur ^= 1;
  }
#pragma unroll
  for (int mf = 0; mf < 4; ++mf)
#pragma unroll
    for (int nf = 0; nf < 4; ++nf)
#pragma unroll
      for (int r = 0; r < 4; ++r) {
        long row = Ar0 + wm * 64 + mf * 16 + l4 * 4 + r;
        long col = Br0 + wn * 64 + nf * 16 + l15;
        float v = acc[mf][nf][r];
        if (OUT_BF16)
          Cb[row * N + col] = (bf16_t)v;
        else
          Cf[row * N + col] = v;
      }
}

// ---------------- RoPE in-place, vectorized: thread = 8 (d,d+32) pairs ----------------
__global__ __launch_bounds__(256) void rope_kernel(bf16_t* __restrict__ qkv,
                                                   const float* __restrict__ cosb,
                                                   const float* __restrict__ sinb) {
  const int head = blockIdx.y;
  const int i = blockIdx.x * 256 + threadIdx.x;
  const long bs = i >> 2;
  const int d0 = (i & 3) * 8;
  const long base = bs * NQKV + (head < 32 ? head * 64 : 2048 + (head - 32) * 64) + d0;
  const float scl = head < 32 ? QSCALE : 1.0f;
  bf16x8 x1 = *(bf16x8*)(qkv + base);
  bf16x8 x2 = *(bf16x8*)(qkv + base + 32);
  const float4* cp = (const float4*)(cosb + bs * 64 + d0);
  const float4* sp = (const float4*)(sinb + bs * 64 + d0);
  const float4 c0 = cp[0], c1 = cp[1];
  const float4 s0 = sp[0], s1 = sp[1];
  const float cc[8] = {c0.x, c0.y, c0.z, c0.w, c1.x, c1.y, c1.z, c1.w};
  const float ss[8] = {s0.x, s0.y, s0.z, s0.w, s1.x, s1.y, s1.z, s1.w};
  bf16x8 y1, y2;
#pragma unroll
  for (int e = 0; e < 8; ++e) {
    const float f1 = (float)x1[e], f2 = (float)x2[e];
    y1[e] = (bf16_t)((f1 * cc[e] - f2 * ss[e]) * scl);
    y2[e] = (bf16_t)((f2 * cc[e] + f1 * ss[e]) * scl);
  }
  *(bf16x8*)(qkv + base) = y1;
  *(bf16x8*)(qkv + base + 32) = y2;
}

// ---------------- V transpose via swizzled LDS tile: coalesced both sides ----------------
__global__ __launch_bounds__(256) void v_transpose(const bf16_t* __restrict__ qkv,
                                                   bf16_t* __restrict__ vT) {
  __shared__ __align__(16) bf16_t lds[64 * 64];
  const int b = blockIdx.z, kvh = blockIdx.y, s0 = blockIdx.x * 64;
  const int t = threadIdx.x;
  auto key = [](int s) { return (((s & 7) ^ ((s >> 3) & 7)) << 3); };
  const int si = t >> 3, j8 = (t & 7) * 8;
  const bf16_t* src = qkv + ((long)(b * S_ + s0 + si)) * NQKV + 2560 + kvh * 64 + j8;
  *(bf16x8*)&lds[si * 64 + (j8 ^ key(si))] = *(const bf16x8*)src;
  *(bf16x8*)&lds[(si + 32) * 64 + (j8 ^ key(si + 32))] =
      *(const bf16x8*)(src + 32L * NQKV);
  __syncthreads();
  const int d = t >> 2, sg = (t & 3) * 16;
  bf16x8 o0, o1;
#pragma unroll
  for (int e = 0; e < 8; ++e) {
    o0[e] = lds[(sg + e) * 64 + (d ^ key(sg + e))];
    o1[e] = lds[(sg + 8 + e) * 64 + (d ^ key(sg + 8 + e))];
  }
  bf16_t* dst = vT + ((long)(b * NKV + kvh) * 64 + d) * S_ + s0 + sg;
  *(bf16x8*)dst = o0;
  *(bf16x8*)(dst + 8) = o1;
}

__device__ __forceinline__ unsigned pkbf16(float lo, float hi) {
  union { bf16_t h[2]; unsigned u; } x;
  x.h[0] = (bf16_t)lo;
  x.h[1] = (bf16_t)hi;
  return x.u;
}

// ---------------- flash attention, causal, GQA — 32x32 MFMA, swapped operands ----------------
// grid (32, 32, 2), 128 threads (2 waves), one 64-row q-tile per block, heavy-first.
// K staged in XOR-swizzled LDS (round-5 proven). V read directly from vT (L1/L2-resident
// 8KB tile, shared by both waves); V loads issued right after QK^T so softmax hides latency.
__global__ __launch_bounds__(128) void attn32_kernel(const bf16_t* __restrict__ qkv,
                                                     const bf16_t* __restrict__ vT,
                                                     bf16_t* __restrict__ y) {
  const int qt = 31 - (int)blockIdx.x;     // heavy blocks first
  const int h = blockIdx.y;
  const int b = blockIdx.z;
  const int kvh = h >> 2;
  const int t = threadIdx.x, lane = t & 63, w = t >> 6;
  const int l31 = lane & 31, hd = lane >> 5;
  const long bS = (long)b * S_;

  __shared__ __align__(16) bf16_t Klds[2][64 * 64];

  const bf16_t* kbase = qkv + bS * NQKV + NH * HD + kvh * 64;       // [s][NQKV] K section
  const bf16_t* vbase = vT + ((long)(b * NKV + kvh)) * 64 * S_;     // [d][S]
  const bf16_t* vlane = vbase + (long)l31 * S_ + hd * 8;            // per-lane V row base

  // K staging: thread covers rows row0+16c (c=0..3), 16B each, XOR-swizzled slot
  const int row0 = t >> 3, slot = t & 7;
  const int wslot8 = ((slot ^ (row0 & 7)) << 3);   // (row0+16c)&7 == row0&7
  const bf16_t* kp[4];
#pragma unroll
  for (int c = 0; c < 4; ++c)
    kp[c] = kbase + (long)(row0 + 16 * c) * NQKV + slot * 8;
  bf16x8 kreg[4];

  auto ldG = [&]() {
#pragma unroll
    for (int c = 0; c < 4; ++c) {
      kreg[c] = *(const bf16x8*)kp[c];
      kp[c] += 64L * NQKV;
    }
  };
  auto wrLDS = [&](int buf) {
#pragma unroll
    for (int c = 0; c < 4; ++c)
      *(bf16x8*)&Klds[buf][(row0 + 16 * c) * 64 + wslot8] = kreg[c];
  };

  const int q0w = qt * 64 + w * 32;
  const int myq = q0w + l31;
  const int NT = qt + 1;

  const bf16_t* qp = qkv + (bS + myq) * NQKV + h * 64 + hd * 8;
  bf16x8 qf[4];
#pragma unroll
  for (int ks = 0; ks < 4; ++ks) qf[ks] = *(const bf16x8*)(qp + ks * 16);

  f32x16 yac[2] = {};
  float m = -1e30f, l = 0.f;

  ldG();
  wrLDS(0);
  __syncthreads();

  for (int kt = 0; kt < NT; ++kt) {
    const int buf = kt & 1;
    const int kv0 = kt * 64;
    if (kt + 1 < NT) ldG();                  // issue next K-tile global loads early

    const bf16_t* Kb = &Klds[buf][0];

    // ---- QK^T ----
    f32x16 sac[2] = {};
    __builtin_amdgcn_s_setprio(1);
#pragma unroll
    for (int ks = 0; ks < 4; ++ks)
#pragma unroll
      for (int kb = 0; kb < 2; ++kb) {
        const int row = kb * 32 + l31;
        const bf16x8 kf =
            *(const bf16x8*)&Kb[row * 64 + (((2 * ks + hd) ^ (row & 7)) << 3)];
        sac[kb] = MFMA32(kf, qf[ks], sac[kb]);
      }
    __builtin_amdgcn_s_setprio(0);

    // ---- V fragments: issue global loads now; softmax below hides L2 latency ----
    bf16x8 vld[4][2];
    {
      const bf16_t* pv0 = vlane + kv0;
#pragma unroll
      for (int ks = 0; ks < 4; ++ks) {
        vld[ks][0] = *(const bf16x8*)(pv0 + ks * 16);
        vld[ks][1] = *(const bf16x8*)(pv0 + 32L * S_ + ks * 16);
      }
    }

    // ---- causal mask (diagonal tiles only) ----
    if (kv0 + 63 > q0w) {
#pragma unroll
      for (int kb = 0; kb < 2; ++kb)
#pragma unroll
        for (int r = 0; r < 16; ++r) {
          const int kv = kv0 + kb * 32 + (r & 3) + 8 * (r >> 2) + 4 * hd;
          if (kv > myq) sac[kb][r] = -3.0e38f;
        }
    }
    // ---- online softmax (q row lane-local; halves combined via 1 shfl) ----
    float pm4[8], sm4[8];
#pragma unroll
    for (int g = 0; g < 8; ++g) {
      const int kb = g >> 2, r = (g & 3) * 4;
      pm4[g] = fmaxf(fmaxf(sac[kb][r], sac[kb][r + 1]),
                     fmaxf(sac[kb][r + 2], sac[kb][r + 3]));
    }
    float pm = fmaxf(fmaxf(fmaxf(pm4[0], pm4[1]), fmaxf(pm4[2], pm4[3])),
                     fmaxf(fmaxf(pm4[4], pm4[5]), fmaxf(pm4[6], pm4[7])));
    pm = fmaxf(pm, __shfl_xor(pm, 32, 64));
    if (!__all(pm <= m + 8.f)) {             // T13 defer-max
      const float mnew = fmaxf(m, pm);
      const float sc = __builtin_amdgcn_exp2f(m - mnew);
      l *= sc;
      yac[0] *= sc;
      yac[1] *= sc;
      m = mnew;
    }
#pragma unroll
    for (int kb = 0; kb < 2; ++kb)
#pragma unroll
      for (int r = 0; r < 16; ++r)
        sac[kb][r] = __builtin_amdgcn_exp2f(sac[kb][r] - m);
#pragma unroll
    for (int g = 0; g < 8; ++g) {
      const int kb = g >> 2, r = (g & 3) * 4;
      sm4[g] = (sac[kb][r] + sac[kb][r + 1]) + (sac[kb][r + 2] + sac[kb][r + 3]);
    }
    l += ((sm4[0] + sm4[1]) + (sm4[2] + sm4[3])) +
         ((sm4[4] + sm4[5]) + (sm4[6] + sm4[7]));   // per-half partial; combined at end
    // ---- pack P^T B-frags in-register (cvt pairs + permlane32_swap) + PV ----
#pragma unroll
    for (int ks = 0; ks < 4; ++ks) {
      const int kb = ks >> 1;
      const int Bv = 8 * (ks & 1);
      unsigned a0 = pkbf16(sac[kb][Bv + 0], sac[kb][Bv + 1]);
      unsigned b0 = pkbf16(sac[kb][Bv + 4], sac[kb][Bv + 5]);
      unsigned a1 = pkbf16(sac[kb][Bv + 2], sac[kb][Bv + 3]);
      unsigned b1 = pkbf16(sac[kb][Bv + 6], sac[kb][Bv + 7]);
      asm("v_permlane32_swap_b32 %0, %1" : "+v"(a0), "+v"(b0));
      asm("v_permlane32_swap_b32 %0, %1" : "+v"(a1), "+v"(b1));
      union { unsigned u[4]; bf16x8 v; } pu;
      pu.u[0] = a0; pu.u[1] = a1; pu.u[2] = b0; pu.u[3] = b1;
      __builtin_amdgcn_s_setprio(1);
#pragma unroll
      for (int db = 0; db < 2; ++db)
        yac[db] = MFMA32(vld[ks][db], pu.v, yac[db]);
      __builtin_amdgcn_s_setprio(0);
    }

    if (kt + 1 < NT) wrLDS(buf ^ 1);         // write-late: K regs -> other LDS buffer
    __syncthreads();
  }

  // ---- epilogue: combine half-sums, normalize, store ----
  l += __shfl_xor(l, 32, 64);
  const float inv = __builtin_amdgcn_rcpf(l);
  bf16_t* yp = y + (bS + myq) * (long)H_ + h * 64;
#pragma unroll
  for (int db = 0; db < 2; ++db)
#pragma unroll
    for (int g = 0; g < 4; ++g) {
      bf16x4 o;
      o[0] = (bf16_t)(yac[db][4 * g + 0] * inv);
      o[1] = (bf16_t)(yac[db][4 * g + 1] * inv);
      o[2] = (bf16_t)(yac[db][4 * g + 2] * inv);
      o[3] = (bf16_t)(yac[db][4 * g + 3] * inv);
      *(bf16x4*)(yp + db * 32 + 8 * g + 4 * hd) = o;
    }
}

extern "C" void kernel_launch(void* const* d_in, const int* in_sizes, int n_in,
                              void* d_out, int out_size, void* d_ws, size_t ws_size,
                              hipStream_t stream) {
  const float* hs = (const float*)d_in[0];
  const float* cosb = (const float*)d_in[1];
  const float* sinb = (const float*)d_in[2];
  const float* Wq = (const float*)d_in[3];
  const float* Wk = (const float*)d_in[4];
  const float* Wv = (const float*)d_in[5];
  const float* Wo = (const float*)d_in[6];
  float* out = (float*)d_out;

  char* ws = (char*)d_ws;
  bf16_t* hsb  = (bf16_t*)(ws);                 // 16,777,216 B
  bf16_t* wqkv = (bf16_t*)(ws + 16777216);      // 12,582,912 B
  bf16_t* wo   = (bf16_t*)(ws + 29360128);      //  8,388,608 B
  bf16_t* qkv  = (bf16_t*)(ws + 37748736);      // 25,165,824 B
  bf16_t* vT   = (bf16_t*)(ws + 62914560);      //  4,194,304 B
  bf16_t* yb   = (bf16_t*)(ws + 67108864);      // 16,777,216 B

  cvt_kernel<<<4096, 256, 0, stream>>>(hs, hsb, 1048576);
  cvt3_kernel<<<3072, 256, 0, stream>>>(Wq, Wk, Wv, wqkv);
  cvt_kernel<<<2048, 256, 0, stream>>>(Wo, wo, 524288);

  // qkv projection (plain bf16 epilogue)
  gemm_bt<true><<<dim3(24, 32), 256, 0, stream>>>(hsb, wqkv, nullptr, qkv,
                                                  M_ROWS, NQKV, H_);
  // rope (vectorized, q scaled)
  rope_kernel<<<dim3(64, 40), 256, 0, stream>>>(qkv, cosb, sinb);
  // v transpose (LDS-tiled)
  v_transpose<<<dim3(32, 8, 2), 256, 0, stream>>>(qkv, vT);
  // attention (un-paired, heavy-first, V direct from L2)
  attn32_kernel<<<dim3(32, 32, 2), 128, 0, stream>>>(qkv, vT, yb);
  // output projection
  gemm_bt<false><<<dim3(16, 32), 256, 0, stream>>>(yb, wo, out, nullptr,
                                                   M_ROWS, H_, H_);
}

// Round 13
// 229.829 us; speedup vs baseline: 1.2542x; 1.2542x over previous
//
#include <hip/hip_runtime.h>

typedef __bf16 bf16_t;
typedef bf16_t bf16x8 __attribute__((ext_vector_type(8)));
typedef bf16_t bf16x4 __attribute__((ext_vector_type(4)));
typedef float f32x4 __attribute__((ext_vector_type(4)));
typedef float f32x16 __attribute__((ext_vector_type(16)));

#define MFMA16(a, b, c) __builtin_amdgcn_mfma_f32_16x16x32_bf16(a, b, c, 0, 0, 0)
#define MFMA32(a, b, c) __builtin_amdgcn_mfma_f32_32x32x16_bf16(a, b, c, 0, 0, 0)

#define GLOAD16(gsrc, ldst)                                            \
  __builtin_amdgcn_global_load_lds(                                    \
      (const __attribute__((address_space(1))) void*)(gsrc),           \
      (__attribute__((address_space(3))) void*)(ldst), 16, 0, 0)

constexpr int B_ = 2, S_ = 2048, H_ = 2048, NH = 32, NKV = 8, HD = 64;
constexpr int NQKV = NH * HD + 2 * NKV * HD;   // 3072
constexpr int M_ROWS = B_ * S_;                // 4096
constexpr float QSCALE = 0.125f * 1.4426950408889634f;  // score-scale * log2(e) folded into q

// ---------------- f32 -> bf16 convert (8 elems/thread) ----------------
__global__ __launch_bounds__(256) void cvt_kernel(const float* __restrict__ in,
                                                  bf16_t* __restrict__ out, int n8) {
  int i = blockIdx.x * 256 + threadIdx.x;
  if (i >= n8) return;
  const float4* p = (const float4*)(in + (size_t)i * 8);
  float4 a = p[0], b = p[1];
  bf16x8 o;
  o[0] = (bf16_t)a.x; o[1] = (bf16_t)a.y; o[2] = (bf16_t)a.z; o[3] = (bf16_t)a.w;
  o[4] = (bf16_t)b.x; o[5] = (bf16_t)b.y; o[6] = (bf16_t)b.z; o[7] = (bf16_t)b.w;
  *(bf16x8*)(out + (size_t)i * 8) = o;
}

// Wq (524288x8) + Wk (131072x8) + Wv (131072x8) -> contiguous wqkv
__global__ __launch_bounds__(256) void cvt3_kernel(const float* __restrict__ s0,
                                                   const float* __restrict__ s1,
                                                   const float* __restrict__ s2,
                                                   bf16_t* __restrict__ out) {
  int i = blockIdx.x * 256 + threadIdx.x;
  const float* src;
  long off;
  if (i < 524288) { src = s0; off = i; }
  else if (i < 655360) { src = s1; off = i - 524288; }
  else { src = s2; off = i - 655360; }
  const float4* p = (const float4*)(src + off * 8);
  float4 a = p[0], b = p[1];
  bf16x8 o;
  o[0] = (bf16_t)a.x; o[1] = (bf16_t)a.y; o[2] = (bf16_t)a.z; o[3] = (bf16_t)a.w;
  o[4] = (bf16_t)b.x; o[5] = (bf16_t)b.y; o[6] = (bf16_t)b.z; o[7] = (bf16_t)b.w;
  *(bf16x8*)(out + (size_t)i * 8) = o;
}

// ---------------- GEMM: C(MxN) = A(MxK) * B(NxK)^T, bf16 in, f32 acc ----------------
// 128x128 tile, BK=32, 4 waves (2x2). global_load_lds(16B) staging, double-buffered,
// source-pre-swizzled LDS for conflict-free ds_read_b128. (round-3 proven form)
template <bool OUT_BF16>
__global__ __launch_bounds__(256) void gemm_bt(const bf16_t* __restrict__ A,
                                               const bf16_t* __restrict__ Bm,
                                               float* __restrict__ Cf,
                                               bf16_t* __restrict__ Cb,
                                               int M, int N, int K) {
  __shared__ __align__(16) bf16_t As[2][128 * 32];
  __shared__ __align__(16) bf16_t Bs[2][128 * 32];
  const int t = threadIdx.x;
  const int lane = t & 63, w = t >> 6;
  const int l15 = lane & 15, l4 = lane >> 4;
  const int wm = w >> 1, wn = w & 1;
  const long Ar0 = (long)blockIdx.y * 128;
  const long Br0 = (long)blockIdx.x * 128;
  const int nt = K >> 5;

  const int scol = ((lane & 3) ^ ((lane >> 3) & 3)) * 8;
  const int srow = lane >> 2;
  auto stage = [&](int kt, int buf) {
#pragma unroll
    for (int c = 0; c < 2; ++c) {
      const int i = w * 2 + c;
      const bf16_t* gA = A + (Ar0 + i * 16 + srow) * (long)K + kt * 32 + scol;
      const bf16_t* gB = Bm + (Br0 + i * 16 + srow) * (long)K + kt * 32 + scol;
      GLOAD16(gA, &As[buf][i * 512]);
      GLOAD16(gB, &Bs[buf][i * 512]);
    }
  };

  f32x4 acc[4][4] = {};
  stage(0, 0);
  __syncthreads();
  int cur = 0;
  const int rsw = l4 ^ ((l15 >> 1) & 3);
  for (int kt = 0; kt < nt; ++kt) {
    if (kt + 1 < nt) stage(kt + 1, cur ^ 1);
    bf16x8 af[4], bfr[4];
#pragma unroll
    for (int mf = 0; mf < 4; ++mf)
      af[mf] = *(const bf16x8*)&As[cur][(wm * 64 + mf * 16 + l15) * 32 + rsw * 8];
#pragma unroll
    for (int nf = 0; nf < 4; ++nf)
      bfr[nf] = *(const bf16x8*)&Bs[cur][(wn * 64 + nf * 16 + l15) * 32 + rsw * 8];
#pragma unroll
    for (int mf = 0; mf < 4; ++mf)
#pragma unroll
      for (int nf = 0; nf < 4; ++nf)
        acc[mf][nf] = MFMA16(af[mf], bfr[nf], acc[mf][nf]);
    __syncthreads();
    cur ^= 1;
  }
#pragma unroll
  for (int mf = 0; mf < 4; ++mf)
#pragma unroll
    for (int nf = 0; nf < 4; ++nf)
#pragma unroll
      for (int r = 0; r < 4; ++r) {
        long row = Ar0 + wm * 64 + mf * 16 + l4 * 4 + r;
        long col = Br0 + wn * 64 + nf * 16 + l15;
        float v = acc[mf][nf][r];
        if (OUT_BF16)
          Cb[row * N + col] = (bf16_t)v;
        else
          Cf[row * N + col] = v;
      }
}

// ---------------- RoPE in-place, vectorized: thread = 8 (d,d+32) pairs ----------------
__global__ __launch_bounds__(256) void rope_kernel(bf16_t* __restrict__ qkv,
                                                   const float* __restrict__ cosb,
                                                   const float* __restrict__ sinb) {
  const int head = blockIdx.y;
  const int i = blockIdx.x * 256 + threadIdx.x;
  const long bs = i >> 2;
  const int d0 = (i & 3) * 8;
  const long base = bs * NQKV + (head < 32 ? head * 64 : 2048 + (head - 32) * 64) + d0;
  const float scl = head < 32 ? QSCALE : 1.0f;
  bf16x8 x1 = *(bf16x8*)(qkv + base);
  bf16x8 x2 = *(bf16x8*)(qkv + base + 32);
  const float4* cp = (const float4*)(cosb + bs * 64 + d0);
  const float4* sp = (const float4*)(sinb + bs * 64 + d0);
  const float4 c0 = cp[0], c1 = cp[1];
  const float4 s0 = sp[0], s1 = sp[1];
  const float cc[8] = {c0.x, c0.y, c0.z, c0.w, c1.x, c1.y, c1.z, c1.w};
  const float ss[8] = {s0.x, s0.y, s0.z, s0.w, s1.x, s1.y, s1.z, s1.w};
  bf16x8 y1, y2;
#pragma unroll
  for (int e = 0; e < 8; ++e) {
    const float f1 = (float)x1[e], f2 = (float)x2[e];
    y1[e] = (bf16_t)((f1 * cc[e] - f2 * ss[e]) * scl);
    y2[e] = (bf16_t)((f2 * cc[e] + f1 * ss[e]) * scl);
  }
  *(bf16x8*)(qkv + base) = y1;
  *(bf16x8*)(qkv + base + 32) = y2;
}

// ---------------- V transpose via swizzled LDS tile: coalesced both sides ----------------
__global__ __launch_bounds__(256) void v_transpose(const bf16_t* __restrict__ qkv,
                                                   bf16_t* __restrict__ vT) {
  __shared__ __align__(16) bf16_t lds[64 * 64];
  const int b = blockIdx.z, kvh = blockIdx.y, s0 = blockIdx.x * 64;
  const int t = threadIdx.x;
  auto key = [](int s) { return (((s & 7) ^ ((s >> 3) & 7)) << 3); };
  const int si = t >> 3, j8 = (t & 7) * 8;
  const bf16_t* src = qkv + ((long)(b * S_ + s0 + si)) * NQKV + 2560 + kvh * 64 + j8;
  *(bf16x8*)&lds[si * 64 + (j8 ^ key(si))] = *(const bf16x8*)src;
  *(bf16x8*)&lds[(si + 32) * 64 + (j8 ^ key(si + 32))] =
      *(const bf16x8*)(src + 32L * NQKV);
  __syncthreads();
  const int d = t >> 2, sg = (t & 3) * 16;
  bf16x8 o0, o1;
#pragma unroll
  for (int e = 0; e < 8; ++e) {
    o0[e] = lds[(sg + e) * 64 + (d ^ key(sg + e))];
    o1[e] = lds[(sg + 8 + e) * 64 + (d ^ key(sg + 8 + e))];
  }
  bf16_t* dst = vT + ((long)(b * NKV + kvh) * 64 + d) * S_ + s0 + sg;
  *(bf16x8*)dst = o0;
  *(bf16x8*)(dst + 8) = o1;
}

__device__ __forceinline__ unsigned pkbf16(float lo, float hi) {
  union { bf16_t h[2]; unsigned u; } x;
  x.h[0] = (bf16_t)lo;
  x.h[1] = (bf16_t)hi;
  return x.u;
}

// ---------------- flash attention, causal, GQA — 32x32 MFMA, swapped operands ----------------
// 512-thread blocks (8 waves): 4 q-heads of one kv-head share the K/V LDS tiles.
// Wave w: head kvh*4 + (w>>1), q rows qt*64 + (w&1)*32 + lane. 1D grid of 512 blocks;
// qt = (bx&1) ? p : 31-p (adjacent blocks complementary for load balance).
// Per-wave inner loop identical to round-5 proven form (XOR-swizzled K/V, shfl_xor
// reductions, cvt-pair + permlane32_swap P-pack, defer-max).
__global__ __launch_bounds__(512, 4) void attn32_kernel(const bf16_t* __restrict__ qkv,
                                                        const bf16_t* __restrict__ vT,
                                                        bf16_t* __restrict__ y) {
  const int bx = blockIdx.x;
  const int p = (bx >> 1) & 15;
  const int qt = (bx & 1) ? p : 31 - p;
  const int kvh = (bx >> 5) & 7;
  const int b = bx >> 8;
  const int t = threadIdx.x, lane = t & 63, w = t >> 6;
  const int l31 = lane & 31, hd = lane >> 5;
  const int h = kvh * 4 + (w >> 1);
  const long bS = (long)b * S_;

  __shared__ __align__(16) bf16_t Klds[2][64 * 64];
  __shared__ __align__(16) bf16_t Vlds[2][64 * 64];

  const bf16_t* kbase = qkv + bS * NQKV + NH * HD + kvh * 64;       // [s][NQKV] K section
  const bf16_t* vbase = vT + ((long)(b * NKV + kvh)) * 64 * S_;     // [d][S]

  // staging: 512 threads x one 16B chunk each for K and V (rows 0..63, slots 0..7)
  const int row0 = t >> 3, slot = t & 7;
  const int wslot8 = ((slot ^ (row0 & 7)) << 3);
  const bf16_t* kp = kbase + (long)row0 * NQKV + slot * 8;
  const bf16_t* vp = vbase + (long)row0 * S_ + slot * 8;
  bf16x8 kreg, vreg;

  auto ldG = [&]() {
    kreg = *(const bf16x8*)kp;
    vreg = *(const bf16x8*)vp;
    kp += 64L * NQKV;
    vp += 64;
  };
  auto wrLDS = [&](int buf) {
    *(bf16x8*)&Klds[buf][row0 * 64 + wslot8] = kreg;
    *(bf16x8*)&Vlds[buf][row0 * 64 + wslot8] = vreg;
  };

  const int q0w = qt * 64 + (w & 1) * 32;
  const int myq = q0w + l31;
  const int NT = qt + 1;

  const bf16_t* qp = qkv + (bS + myq) * NQKV + h * 64 + hd * 8;
  bf16x8 qf[4];
#pragma unroll
  for (int ks = 0; ks < 4; ++ks) qf[ks] = *(const bf16x8*)(qp + ks * 16);

  f32x16 yac[2] = {};
  float m = -1e30f, l = 0.f;

  ldG();
  wrLDS(0);
  __syncthreads();

  for (int kt = 0; kt < NT; ++kt) {
    const int buf = kt & 1;
    const int kv0 = kt * 64;
    if (kt + 1 < NT) ldG();                  // issue next-tile global loads early

    const bf16_t* Kb = &Klds[buf][0];
    const bf16_t* Vb = &Vlds[buf][0];

    // ---- QK^T ----
    f32x16 sac[2] = {};
    __builtin_amdgcn_s_setprio(1);
#pragma unroll
    for (int ks = 0; ks < 4; ++ks)
#pragma unroll
      for (int kb = 0; kb < 2; ++kb) {
        const int row = kb * 32 + l31;
        const bf16x8 kf =
            *(const bf16x8*)&Kb[row * 64 + (((2 * ks + hd) ^ (row & 7)) << 3)];
        sac[kb] = MFMA32(kf, qf[ks], sac[kb]);
      }
    __builtin_amdgcn_s_setprio(0);
    // ---- causal mask (diagonal tiles only) ----
    if (kv0 + 63 > q0w) {
#pragma unroll
      for (int kb = 0; kb < 2; ++kb)
#pragma unroll
        for (int r = 0; r < 16; ++r) {
          const int kv = kv0 + kb * 32 + (r & 3) + 8 * (r >> 2) + 4 * hd;
          if (kv > myq) sac[kb][r] = -3.0e38f;
        }
    }
    // ---- online softmax (q row lane-local; halves combined via 1 shfl) ----
    float pm4[8], sm4[8];
#pragma unroll
    for (int g = 0; g < 8; ++g) {
      const int kb = g >> 2, r = (g & 3) * 4;
      pm4[g] = fmaxf(fmaxf(sac[kb][r], sac[kb][r + 1]),
                     fmaxf(sac[kb][r + 2], sac[kb][r + 3]));
    }
    float pm = fmaxf(fmaxf(fmaxf(pm4[0], pm4[1]), fmaxf(pm4[2], pm4[3])),
                     fmaxf(fmaxf(pm4[4], pm4[5]), fmaxf(pm4[6], pm4[7])));
    pm = fmaxf(pm, __shfl_xor(pm, 32, 64));
    if (!__all(pm <= m + 8.f)) {             // T13 defer-max
      const float mnew = fmaxf(m, pm);
      const float sc = __builtin_amdgcn_exp2f(m - mnew);
      l *= sc;
      yac[0] *= sc;
      yac[1] *= sc;
      m = mnew;
    }
#pragma unroll
    for (int kb = 0; kb < 2; ++kb)
#pragma unroll
      for (int r = 0; r < 16; ++r)
        sac[kb][r] = __builtin_amdgcn_exp2f(sac[kb][r] - m);
#pragma unroll
    for (int g = 0; g < 8; ++g) {
      const int kb = g >> 2, r = (g & 3) * 4;
      sm4[g] = (sac[kb][r] + sac[kb][r + 1]) + (sac[kb][r + 2] + sac[kb][r + 3]);
    }
    l += ((sm4[0] + sm4[1]) + (sm4[2] + sm4[3])) +
         ((sm4[4] + sm4[5]) + (sm4[6] + sm4[7]));   // per-half partial; combined at end
    // ---- pack P^T B-frags in-register (cvt pairs + permlane32_swap) + PV ----
#pragma unroll
    for (int ks = 0; ks < 4; ++ks) {
      const int kb = ks >> 1;
      const int Bv = 8 * (ks & 1);
      unsigned a0 = pkbf16(sac[kb][Bv + 0], sac[kb][Bv + 1]);
      unsigned b0 = pkbf16(sac[kb][Bv + 4], sac[kb][Bv + 5]);
      unsigned a1 = pkbf16(sac[kb][Bv + 2], sac[kb][Bv + 3]);
      unsigned b1 = pkbf16(sac[kb][Bv + 6], sac[kb][Bv + 7]);
      asm("v_permlane32_swap_b32 %0, %1" : "+v"(a0), "+v"(b0));
      asm("v_permlane32_swap_b32 %0, %1" : "+v"(a1), "+v"(b1));
      union { unsigned u[4]; bf16x8 v; } pu;
      pu.u[0] = a0; pu.u[1] = a1; pu.u[2] = b0; pu.u[3] = b1;
      __builtin_amdgcn_s_setprio(1);
#pragma unroll
      for (int db = 0; db < 2; ++db) {
        const int row = db * 32 + l31;
        const bf16x8 vf =
            *(const bf16x8*)&Vb[row * 64 + (((2 * ks + hd) ^ (row & 7)) << 3)];
        yac[db] = MFMA32(vf, pu.v, yac[db]);
      }
      __builtin_amdgcn_s_setprio(0);
    }

    if (kt + 1 < NT) wrLDS(buf ^ 1);         // write-late: regs -> other LDS buffer
    __syncthreads();
  }

  // ---- epilogue: combine half-sums, normalize, store ----
  l += __shfl_xor(l, 32, 64);
  const float inv = __builtin_amdgcn_rcpf(l);
  bf16_t* yp = y + (bS + myq) * (long)H_ + h * 64;
#pragma unroll
  for (int db = 0; db < 2; ++db)
#pragma unroll
    for (int g = 0; g < 4; ++g) {
      bf16x4 o;
      o[0] = (bf16_t)(yac[db][4 * g + 0] * inv);
      o[1] = (bf16_t)(yac[db][4 * g + 1] * inv);
      o[2] = (bf16_t)(yac[db][4 * g + 2] * inv);
      o[3] = (bf16_t)(yac[db][4 * g + 3] * inv);
      *(bf16x4*)(yp + db * 32 + 8 * g + 4 * hd) = o;
    }
}

extern "C" void kernel_launch(void* const* d_in, const int* in_sizes, int n_in,
                              void* d_out, int out_size, void* d_ws, size_t ws_size,
                              hipStream_t stream) {
  const float* hs = (const float*)d_in[0];
  const float* cosb = (const float*)d_in[1];
  const float* sinb = (const float*)d_in[2];
  const float* Wq = (const float*)d_in[3];
  const float* Wk = (const float*)d_in[4];
  const float* Wv = (const float*)d_in[5];
  const float* Wo = (const float*)d_in[6];
  float* out = (float*)d_out;

  char* ws = (char*)d_ws;
  bf16_t* hsb  = (bf16_t*)(ws);                 // 16,777,216 B
  bf16_t* wqkv = (bf16_t*)(ws + 16777216);      // 12,582,912 B
  bf16_t* wo   = (bf16_t*)(ws + 29360128);      //  8,388,608 B
  bf16_t* qkv  = (bf16_t*)(ws + 37748736);      // 25,165,824 B
  bf16_t* vT   = (bf16_t*)(ws + 62914560);      //  4,194,304 B
  bf16_t* yb   = (bf16_t*)(ws + 67108864);      // 16,777,216 B

  cvt_kernel<<<4096, 256, 0, stream>>>(hs, hsb, 1048576);
  cvt3_kernel<<<3072, 256, 0, stream>>>(Wq, Wk, Wv, wqkv);
  cvt_kernel<<<2048, 256, 0, stream>>>(Wo, wo, 524288);

  // qkv projection (plain bf16 epilogue)
  gemm_bt<true><<<dim3(24, 32), 256, 0, stream>>>(hsb, wqkv, nullptr, qkv,
                                                  M_ROWS, NQKV, H_);
  // rope (vectorized, q scaled)
  rope_kernel<<<dim3(64, 40), 256, 0, stream>>>(qkv, cosb, sinb);
  // v transpose (LDS-tiled)
  v_transpose<<<dim3(32, 8, 2), 256, 0, stream>>>(qkv, vT);
  // attention (8-wave blocks: 4 q-heads share K/V LDS; 512 blocks, balanced qt)
  attn32_kernel<<<512, 512, 0, stream>>>(qkv, vT, yb);
  // output projection
  gemm_bt<false><<<dim3(16, 32), 256, 0, stream>>>(yb, wo, out, nullptr,
                                                   M_ROWS, H_, H_);
}

// Round 14
// 206.844 us; speedup vs baseline: 1.3935x; 1.1111x over previous
//
#include <hip/hip_runtime.h>

typedef __bf16 bf16_t;
typedef bf16_t bf16x8 __attribute__((ext_vector_type(8)));
typedef bf16_t bf16x4 __attribute__((ext_vector_type(4)));
typedef float f32x4 __attribute__((ext_vector_type(4)));
typedef float f32x16 __attribute__((ext_vector_type(16)));

#define MFMA16(a, b, c) __builtin_amdgcn_mfma_f32_16x16x32_bf16(a, b, c, 0, 0, 0)
#define MFMA32(a, b, c) __builtin_amdgcn_mfma_f32_32x32x16_bf16(a, b, c, 0, 0, 0)

#define GLOAD16(gsrc, ldst)                                            \
  __builtin_amdgcn_global_load_lds(                                    \
      (const __attribute__((address_space(1))) void*)(gsrc),           \
      (__attribute__((address_space(3))) void*)(ldst), 16, 0, 0)

constexpr int B_ = 2, S_ = 2048, H_ = 2048, NH = 32, NKV = 8, HD = 64;
constexpr int NQKV = NH * HD + 2 * NKV * HD;   // 3072
constexpr int M_ROWS = B_ * S_;                // 4096
constexpr float QSCALE = 0.125f * 1.4426950408889634f;  // score-scale * log2(e) folded into q

// ---------------- all f32 -> bf16 converts in ONE kernel (8 elems/thread) ----------------
// chunk ranges: [0,1048576) hs->hsb | [..,+524288) Wq | +131072 Wk | +131072 Wv -> wqkv | +524288 Wo -> wo
__global__ __launch_bounds__(256) void cvt_all(const float* __restrict__ hs,
                                               const float* __restrict__ Wq,
                                               const float* __restrict__ Wk,
                                               const float* __restrict__ Wv,
                                               const float* __restrict__ Wo,
                                               bf16_t* __restrict__ hsb,
                                               bf16_t* __restrict__ wqkv,
                                               bf16_t* __restrict__ wo) {
  const long i = (long)blockIdx.x * 256 + threadIdx.x;
  const float* src;
  bf16_t* dst;
  if (i < 1048576) {
    src = hs + i * 8;            dst = hsb + i * 8;
  } else if (i < 1572864) {
    const long j = i - 1048576;  src = Wq + j * 8;  dst = wqkv + j * 8;
  } else if (i < 1703936) {
    const long j = i - 1572864;  src = Wk + j * 8;  dst = wqkv + 4194304 + j * 8;
  } else if (i < 1835008) {
    const long j = i - 1703936;  src = Wv + j * 8;  dst = wqkv + 5242880 + j * 8;
  } else {
    const long j = i - 1835008;  src = Wo + j * 8;  dst = wo + j * 8;
  }
  const float4* p = (const float4*)src;
  float4 a = p[0], b = p[1];
  bf16x8 o;
  o[0] = (bf16_t)a.x; o[1] = (bf16_t)a.y; o[2] = (bf16_t)a.z; o[3] = (bf16_t)a.w;
  o[4] = (bf16_t)b.x; o[5] = (bf16_t)b.y; o[6] = (bf16_t)b.z; o[7] = (bf16_t)b.w;
  *(bf16x8*)dst = o;
}

// ---------------- GEMM: C(MxN) = A(MxK) * B(NxK)^T, bf16 in, f32 acc ----------------
// 128x128 tile, BK=32, 4 waves (2x2). global_load_lds(16B) staging, double-buffered,
// source-pre-swizzled LDS for conflict-free ds_read_b128. (round-3 proven form)
template <bool OUT_BF16>
__global__ __launch_bounds__(256) void gemm_bt(const bf16_t* __restrict__ A,
                                               const bf16_t* __restrict__ Bm,
                                               float* __restrict__ Cf,
                                               bf16_t* __restrict__ Cb,
                                               int M, int N, int K) {
  __shared__ __align__(16) bf16_t As[2][128 * 32];
  __shared__ __align__(16) bf16_t Bs[2][128 * 32];
  const int t = threadIdx.x;
  const int lane = t & 63, w = t >> 6;
  const int l15 = lane & 15, l4 = lane >> 4;
  const int wm = w >> 1, wn = w & 1;
  const long Ar0 = (long)blockIdx.y * 128;
  const long Br0 = (long)blockIdx.x * 128;
  const int nt = K >> 5;

  const int scol = ((lane & 3) ^ ((lane >> 3) & 3)) * 8;
  const int srow = lane >> 2;
  auto stage = [&](int kt, int buf) {
#pragma unroll
    for (int c = 0; c < 2; ++c) {
      const int i = w * 2 + c;
      const bf16_t* gA = A + (Ar0 + i * 16 + srow) * (long)K + kt * 32 + scol;
      const bf16_t* gB = Bm + (Br0 + i * 16 + srow) * (long)K + kt * 32 + scol;
      GLOAD16(gA, &As[buf][i * 512]);
      GLOAD16(gB, &Bs[buf][i * 512]);
    }
  };

  f32x4 acc[4][4] = {};
  stage(0, 0);
  __syncthreads();
  int cur = 0;
  const int rsw = l4 ^ ((l15 >> 1) & 3);
  for (int kt = 0; kt < nt; ++kt) {
    if (kt + 1 < nt) stage(kt + 1, cur ^ 1);
    bf16x8 af[4], bfr[4];
#pragma unroll
    for (int mf = 0; mf < 4; ++mf)
      af[mf] = *(const bf16x8*)&As[cur][(wm * 64 + mf * 16 + l15) * 32 + rsw * 8];
#pragma unroll
    for (int nf = 0; nf < 4; ++nf)
      bfr[nf] = *(const bf16x8*)&Bs[cur][(wn * 64 + nf * 16 + l15) * 32 + rsw * 8];
#pragma unroll
    for (int mf = 0; mf < 4; ++mf)
#pragma unroll
      for (int nf = 0; nf < 4; ++nf)
        acc[mf][nf] = MFMA16(af[mf], bfr[nf], acc[mf][nf]);
    __syncthreads();
    cur ^= 1;
  }
#pragma unroll
  for (int mf = 0; mf < 4; ++mf)
#pragma unroll
    for (int nf = 0; nf < 4; ++nf)
#pragma unroll
      for (int r = 0; r < 4; ++r) {
        long row = Ar0 + wm * 64 + mf * 16 + l4 * 4 + r;
        long col = Br0 + wn * 64 + nf * 16 + l15;
        float v = acc[mf][nf][r];
        if (OUT_BF16)
          Cb[row * N + col] = (bf16_t)v;
        else
          Cf[row * N + col] = v;
      }
}

// ---------------- RoPE in-place, vectorized: thread = 8 (d,d+32) pairs ----------------
__global__ __launch_bounds__(256) void rope_kernel(bf16_t* __restrict__ qkv,
                                                   const float* __restrict__ cosb,
                                                   const float* __restrict__ sinb) {
  const int head = blockIdx.y;
  const int i = blockIdx.x * 256 + threadIdx.x;
  const long bs = i >> 2;
  const int d0 = (i & 3) * 8;
  const long base = bs * NQKV + (head < 32 ? head * 64 : 2048 + (head - 32) * 64) + d0;
  const float scl = head < 32 ? QSCALE : 1.0f;
  bf16x8 x1 = *(bf16x8*)(qkv + base);
  bf16x8 x2 = *(bf16x8*)(qkv + base + 32);
  const float4* cp = (const float4*)(cosb + bs * 64 + d0);
  const float4* sp = (const float4*)(sinb + bs * 64 + d0);
  const float4 c0 = cp[0], c1 = cp[1];
  const float4 s0 = sp[0], s1 = sp[1];
  const float cc[8] = {c0.x, c0.y, c0.z, c0.w, c1.x, c1.y, c1.z, c1.w};
  const float ss[8] = {s0.x, s0.y, s0.z, s0.w, s1.x, s1.y, s1.z, s1.w};
  bf16x8 y1, y2;
#pragma unroll
  for (int e = 0; e < 8; ++e) {
    const float f1 = (float)x1[e], f2 = (float)x2[e];
    y1[e] = (bf16_t)((f1 * cc[e] - f2 * ss[e]) * scl);
    y2[e] = (bf16_t)((f2 * cc[e] + f1 * ss[e]) * scl);
  }
  *(bf16x8*)(qkv + base) = y1;
  *(bf16x8*)(qkv + base + 32) = y2;
}

// ---------------- V transpose via swizzled LDS tile: coalesced both sides ----------------
__global__ __launch_bounds__(256) void v_transpose(const bf16_t* __restrict__ qkv,
                                                   bf16_t* __restrict__ vT) {
  __shared__ __align__(16) bf16_t lds[64 * 64];
  const int b = blockIdx.z, kvh = blockIdx.y, s0 = blockIdx.x * 64;
  const int t = threadIdx.x;
  auto key = [](int s) { return (((s & 7) ^ ((s >> 3) & 7)) << 3); };
  const int si = t >> 3, j8 = (t & 7) * 8;
  const bf16_t* src = qkv + ((long)(b * S_ + s0 + si)) * NQKV + 2560 + kvh * 64 + j8;
  *(bf16x8*)&lds[si * 64 + (j8 ^ key(si))] = *(const bf16x8*)src;
  *(bf16x8*)&lds[(si + 32) * 64 + (j8 ^ key(si + 32))] =
      *(const bf16x8*)(src + 32L * NQKV);
  __syncthreads();
  const int d = t >> 2, sg = (t & 3) * 16;
  bf16x8 o0, o1;
#pragma unroll
  for (int e = 0; e < 8; ++e) {
    o0[e] = lds[(sg + e) * 64 + (d ^ key(sg + e))];
    o1[e] = lds[(sg + 8 + e) * 64 + (d ^ key(sg + 8 + e))];
  }
  bf16_t* dst = vT + ((long)(b * NKV + kvh) * 64 + d) * S_ + s0 + sg;
  *(bf16x8*)dst = o0;
  *(bf16x8*)(dst + 8) = o1;
}

__device__ __forceinline__ unsigned pkbf16(float lo, float hi) {
  union { bf16_t h[2]; unsigned u; } x;
  x.h[0] = (bf16_t)lo;
  x.h[1] = (bf16_t)hi;
  return x.u;
}

// ---------------- flash attention, causal, GQA — 32x32 MFMA, swapped operands ----------------
// 512 blocks x 256 threads (4 waves = 2 heads x 2 row-halves sharing K/V LDS).
// Each block processes q-tiles {31-p, p} INTERNALLY -> exactly 33 kv-tile-units per block,
// uniform regardless of XCD assignment (round-13 lesson: parity-based cross-block pairing
// anti-correlates with 8-XCD round-robin dispatch).
// Padded LDS row stride 72 elems (144 B): 0 measured bank conflicts (round 11), and with
// 2-chunk staging the VGPR cost of padding is negligible (round-11's regression was its
// 4-chunk staging register bloat).
__global__ __launch_bounds__(256, 4) void attn32_kernel(const bf16_t* __restrict__ qkv,
                                                        const bf16_t* __restrict__ vT,
                                                        bf16_t* __restrict__ y) {
  constexpr int LSTR = 72;
  const int bx = blockIdx.x;
  const int p = bx & 15;
  const int hp = (bx >> 4) & 1;
  const int kvh = (bx >> 5) & 7;
  const int b = bx >> 8;
  const int t = threadIdx.x, lane = t & 63, w = t >> 6;
  const int l31 = lane & 31, hd = lane >> 5;
  const int h = kvh * 4 + hp * 2 + (w >> 1);
  const long bS = (long)b * S_;

  __shared__ __align__(16) bf16_t Klds[2][64 * LSTR];
  __shared__ __align__(16) bf16_t Vlds[2][64 * LSTR];

  const bf16_t* kbase = qkv + bS * NQKV + NH * HD + kvh * 64;       // [s][NQKV] K section
  const bf16_t* vbase = vT + ((long)(b * NKV + kvh)) * 64 * S_;     // [d][S]

  // staging: 256 threads x 2 chunks of 16B (rows row0, row0+32; slot = t&7)
  const int row0 = t >> 3, slot = t & 7;
  int woff[2];
#pragma unroll
  for (int c = 0; c < 2; ++c) woff[c] = (row0 + 32 * c) * LSTR + slot * 8;
  int roff[4][2];
#pragma unroll
  for (int ks = 0; ks < 4; ++ks)
#pragma unroll
    for (int kb = 0; kb < 2; ++kb)
      roff[ks][kb] = (kb * 32 + l31) * LSTR + (2 * ks + hd) * 8;

  const bf16_t* kp0[2];
  const bf16_t* vp0[2];
#pragma unroll
  for (int c = 0; c < 2; ++c) {
    kp0[c] = kbase + (long)(row0 + 32 * c) * NQKV + slot * 8;
    vp0[c] = vbase + (long)(row0 + 32 * c) * S_ + slot * 8;
  }

  bf16x8 kreg[2], vreg[2];

  for (int half = 0; half < 2; ++half) {
    const int qt = half ? p : 31 - p;
    const int q0w = qt * 64 + (w & 1) * 32;
    const int myq = q0w + l31;
    const int NT = qt + 1;

    const bf16_t* qp = qkv + (bS + myq) * NQKV + h * 64 + hd * 8;
    bf16x8 qf[4];
#pragma unroll
    for (int ks = 0; ks < 4; ++ks) qf[ks] = *(const bf16x8*)(qp + ks * 16);

    const bf16_t* kp[2];
    const bf16_t* vp[2];
#pragma unroll
    for (int c = 0; c < 2; ++c) { kp[c] = kp0[c]; vp[c] = vp0[c]; }

    auto ldG = [&]() {   // load next kv tile into regs; advance pointers
#pragma unroll
      for (int c = 0; c < 2; ++c) {
        kreg[c] = *(const bf16x8*)kp[c];
        vreg[c] = *(const bf16x8*)vp[c];
        kp[c] += 64L * NQKV;
        vp[c] += 64;
      }
    };
    auto wrLDS = [&](int buf) {
#pragma unroll
      for (int c = 0; c < 2; ++c) {
        *(bf16x8*)&Klds[buf][woff[c]] = kreg[c];
        *(bf16x8*)&Vlds[buf][woff[c]] = vreg[c];
      }
    };

    f32x16 yac[2] = {};
    float m = -1e30f, l = 0.f;

    ldG();
    wrLDS(0);
    __syncthreads();

    for (int kt = 0; kt < NT; ++kt) {
      const int buf = kt & 1;
      const int kv0 = kt * 64;
      if (kt + 1 < NT) ldG();                  // issue next-tile global loads early

      const bf16_t* Kb = &Klds[buf][0];
      const bf16_t* Vb = &Vlds[buf][0];

      // ---- QK^T ----
      f32x16 sac[2] = {};
      __builtin_amdgcn_s_setprio(1);
#pragma unroll
      for (int ks = 0; ks < 4; ++ks)
#pragma unroll
        for (int kb = 0; kb < 2; ++kb)
          sac[kb] = MFMA32(*(const bf16x8*)&Kb[roff[ks][kb]], qf[ks], sac[kb]);
      __builtin_amdgcn_s_setprio(0);
      // ---- causal mask (diagonal tiles only) ----
      if (kv0 + 63 > q0w) {
#pragma unroll
        for (int kb = 0; kb < 2; ++kb)
#pragma unroll
          for (int r = 0; r < 16; ++r) {
            const int kv = kv0 + kb * 32 + (r & 3) + 8 * (r >> 2) + 4 * hd;
            if (kv > myq) sac[kb][r] = -3.0e38f;
          }
      }
      // ---- online softmax (q row lane-local; halves combined via 1 shfl) ----
      float pm4[8], sm4[8];
#pragma unroll
      for (int g = 0; g < 8; ++g) {
        const int kb = g >> 2, r = (g & 3) * 4;
        pm4[g] = fmaxf(fmaxf(sac[kb][r], sac[kb][r + 1]),
                       fmaxf(sac[kb][r + 2], sac[kb][r + 3]));
      }
      float pm = fmaxf(fmaxf(fmaxf(pm4[0], pm4[1]), fmaxf(pm4[2], pm4[3])),
                       fmaxf(fmaxf(pm4[4], pm4[5]), fmaxf(pm4[6], pm4[7])));
      pm = fmaxf(pm, __shfl_xor(pm, 32, 64));
      if (!__all(pm <= m + 8.f)) {             // T13 defer-max
        const float mnew = fmaxf(m, pm);
        const float sc = __builtin_amdgcn_exp2f(m - mnew);
        l *= sc;
        yac[0] *= sc;
        yac[1] *= sc;
        m = mnew;
      }
#pragma unroll
      for (int kb = 0; kb < 2; ++kb)
#pragma unroll
        for (int r = 0; r < 16; ++r)
          sac[kb][r] = __builtin_amdgcn_exp2f(sac[kb][r] - m);
#pragma unroll
      for (int g = 0; g < 8; ++g) {
        const int kb = g >> 2, r = (g & 3) * 4;
        sm4[g] = (sac[kb][r] + sac[kb][r + 1]) + (sac[kb][r + 2] + sac[kb][r + 3]);
      }
      l += ((sm4[0] + sm4[1]) + (sm4[2] + sm4[3])) +
           ((sm4[4] + sm4[5]) + (sm4[6] + sm4[7]));   // per-half partial; combined at end
      // ---- pack P^T B-frags in-register (cvt pairs + permlane32_swap) + PV ----
#pragma unroll
      for (int ks = 0; ks < 4; ++ks) {
        const int kb = ks >> 1;
        const int Bv = 8 * (ks & 1);
        unsigned a0 = pkbf16(sac[kb][Bv + 0], sac[kb][Bv + 1]);
        unsigned b0 = pkbf16(sac[kb][Bv + 4], sac[kb][Bv + 5]);
        unsigned a1 = pkbf16(sac[kb][Bv + 2], sac[kb][Bv + 3]);
        unsigned b1 = pkbf16(sac[kb][Bv + 6], sac[kb][Bv + 7]);
        asm("v_permlane32_swap_b32 %0, %1" : "+v"(a0), "+v"(b0));
        asm("v_permlane32_swap_b32 %0, %1" : "+v"(a1), "+v"(b1));
        union { unsigned u[4]; bf16x8 v; } pu;
        pu.u[0] = a0; pu.u[1] = a1; pu.u[2] = b0; pu.u[3] = b1;
        __builtin_amdgcn_s_setprio(1);
#pragma unroll
        for (int db = 0; db < 2; ++db)
          yac[db] = MFMA32(*(const bf16x8*)&Vb[roff[ks][db]], pu.v, yac[db]);
        __builtin_amdgcn_s_setprio(0);
      }

      if (kt + 1 < NT) wrLDS(buf ^ 1);         // write-late: regs -> other LDS buffer
      __syncthreads();
    }

    // ---- epilogue: combine half-sums, normalize, store ----
    l += __shfl_xor(l, 32, 64);
    const float inv = __builtin_amdgcn_rcpf(l);
    bf16_t* yp = y + (bS + myq) * (long)H_ + h * 64;
#pragma unroll
    for (int db = 0; db < 2; ++db)
#pragma unroll
      for (int g = 0; g < 4; ++g) {
        bf16x4 o;
        o[0] = (bf16_t)(yac[db][4 * g + 0] * inv);
        o[1] = (bf16_t)(yac[db][4 * g + 1] * inv);
        o[2] = (bf16_t)(yac[db][4 * g + 2] * inv);
        o[3] = (bf16_t)(yac[db][4 * g + 3] * inv);
        *(bf16x4*)(yp + db * 32 + 8 * g + 4 * hd) = o;
      }
  }
}

extern "C" void kernel_launch(void* const* d_in, const int* in_sizes, int n_in,
                              void* d_out, int out_size, void* d_ws, size_t ws_size,
                              hipStream_t stream) {
  const float* hs = (const float*)d_in[0];
  const float* cosb = (const float*)d_in[1];
  const float* sinb = (const float*)d_in[2];
  const float* Wq = (const float*)d_in[3];
  const float* Wk = (const float*)d_in[4];
  const float* Wv = (const float*)d_in[5];
  const float* Wo = (const float*)d_in[6];
  float* out = (float*)d_out;

  char* ws = (char*)d_ws;
  bf16_t* hsb  = (bf16_t*)(ws);                 // 16,777,216 B
  bf16_t* wqkv = (bf16_t*)(ws + 16777216);      // 12,582,912 B
  bf16_t* wo   = (bf16_t*)(ws + 29360128);      //  8,388,608 B
  bf16_t* qkv  = (bf16_t*)(ws + 37748736);      // 25,165,824 B
  bf16_t* vT   = (bf16_t*)(ws + 62914560);      //  4,194,304 B
  bf16_t* yb   = (bf16_t*)(ws + 67108864);      // 16,777,216 B

  // all converts fused
  cvt_all<<<9216, 256, 0, stream>>>(hs, Wq, Wk, Wv, Wo, hsb, wqkv, wo);

  // qkv projection (plain bf16 epilogue)
  gemm_bt<true><<<dim3(24, 32), 256, 0, stream>>>(hsb, wqkv, nullptr, qkv,
                                                  M_ROWS, NQKV, H_);
  // rope (vectorized, q scaled)
  rope_kernel<<<dim3(64, 40), 256, 0, stream>>>(qkv, cosb, sinb);
  // v transpose (LDS-tiled)
  v_transpose<<<dim3(32, 8, 2), 256, 0, stream>>>(qkv, vT);
  // attention (4-wave blocks, 2 heads share K/V, internal q-tile pairing, padded LDS)
  attn32_kernel<<<512, 256, 0, stream>>>(qkv, vT, yb);
  // output projection
  gemm_bt<false><<<dim3(16, 32), 256, 0, stream>>>(yb, wo, out, nullptr,
                                                   M_ROWS, H_, H_);
}